// Round 2
// baseline (607.224 us; speedup 1.0000x reference)
//
#include <hip/hip_runtime.h>
#include <hip/hip_bf16.h>
#include <stdint.h>

#define OUT_F 8192
#define IN_F  8192
#define RANK  16
#define M_TOT 1024   // B*S
#define BM 128
#define BN 128
#define BK 64
#define NK (IN_F / BK)   // 128
#define SCB (IN_F / 32)  // 256 scale blocks per weight row

typedef __bf16 bf16x8 __attribute__((ext_vector_type(8)));
typedef float  f32x4  __attribute__((ext_vector_type(4)));

// round-half-up f32->bf16 pack of two floats into one uint32 (lo in low half)
static __device__ __forceinline__ uint32_t pack_bf16(float lo, float hi) {
    uint32_t a = __builtin_bit_cast(uint32_t, lo);
    uint32_t b = __builtin_bit_cast(uint32_t, hi);
    return ((a + 0x8000u) >> 16) | ((b + 0x8000u) & 0xffff0000u);
}

// ---------------------------------------------------------------------------
// Kernel 1: streaming fp32 -> bf16 convert of x into ws; blocks 0..63 also
// zero t (stream order guarantees t is zeroed before lora_t_kernel runs).
// ---------------------------------------------------------------------------
__global__ __launch_bounds__(256) void convert_kernel(
    const float* __restrict__ x, uint2* __restrict__ xb2, float* __restrict__ t)
{
    const int tid = threadIdx.x, b = blockIdx.x;
    if (b < 64) t[b * 256 + tid] = 0.f;
    const float4* x4 = (const float4*)x;
    const int base = b * 256 + tid;
#pragma unroll
    for (int j = 0; j < 8; ++j) {
        const int i = base + j * 262144;       // 2M float4 total
        const float4 v = x4[i];
        uint2 p;
        p.x = pack_bf16(v.x, v.y);
        p.y = pack_bf16(v.z, v.w);
        xb2[i] = p;
    }
}

// ---------------------------------------------------------------------------
// Kernel 1b: narrow q int32 -> u8, IDENTICAL layout (qu8[o][i] = (u8)q[o][i]).
// Pure streaming identity copy: thread handles 16 consecutive ints.
// 256 MB read + 64 MB write, fully coalesced.
// ---------------------------------------------------------------------------
__global__ __launch_bounds__(256) void narrow_kernel(
    const int* __restrict__ q, uint8_t* __restrict__ qu8)
{
    const size_t base = ((size_t)blockIdx.x * 256 + threadIdx.x) * 16;
    const int4* src = (const int4*)(q + base);
    const int4 a = src[0], b = src[1], c = src[2], d = src[3];
    uint4 o;
    o.x = (uint32_t)a.x | ((uint32_t)a.y << 8) | ((uint32_t)a.z << 16) | ((uint32_t)a.w << 24);
    o.y = (uint32_t)b.x | ((uint32_t)b.y << 8) | ((uint32_t)b.z << 16) | ((uint32_t)b.w << 24);
    o.z = (uint32_t)c.x | ((uint32_t)c.y << 8) | ((uint32_t)c.z << 16) | ((uint32_t)c.w << 24);
    o.w = (uint32_t)d.x | ((uint32_t)d.y << 8) | ((uint32_t)d.z << 16) | ((uint32_t)d.w << 24);
    *(uint4*)(qu8 + base) = o;
}

// ---------------------------------------------------------------------------
// Kernel 2: t = x @ lora_A^T via MFMA split-K + atomicAdd.
// ---------------------------------------------------------------------------
__global__ __launch_bounds__(256) void lora_t_kernel(
    const float* __restrict__ x, const float* __restrict__ lora_A,
    float* __restrict__ t)
{
    const int b = blockIdx.x;
    const int mt = b >> 4, ks = b & 15;
    const int tid = threadIdx.x, wave = tid >> 6, lane = tid & 63;
    const int fr = lane & 15, quad = lane >> 4;
    const int m = mt * 64 + wave * 16 + fr;
    const int k0 = ks * 512 + quad * 8;

    f32x4 acc = {0.f, 0.f, 0.f, 0.f};
    const float* xr = x + (size_t)m * IN_F + k0;
    const float* ar = lora_A + (size_t)fr * IN_F + k0;

#pragma unroll 4
    for (int s = 0; s < 16; ++s) {
        const float4 x0 = *(const float4*)(xr + s * 32);
        const float4 x1 = *(const float4*)(xr + s * 32 + 4);
        const float4 a0 = *(const float4*)(ar + s * 32);
        const float4 a1 = *(const float4*)(ar + s * 32 + 4);
        bf16x8 af, bfr;
        uint32_t* ap = (uint32_t*)&af;
        uint32_t* bp = (uint32_t*)&bfr;
        ap[0] = pack_bf16(x0.x, x0.y); ap[1] = pack_bf16(x0.z, x0.w);
        ap[2] = pack_bf16(x1.x, x1.y); ap[3] = pack_bf16(x1.z, x1.w);
        bp[0] = pack_bf16(a0.x, a0.y); bp[1] = pack_bf16(a0.z, a0.w);
        bp[2] = pack_bf16(a1.x, a1.y); bp[3] = pack_bf16(a1.z, a1.w);
        acc = __builtin_amdgcn_mfma_f32_16x16x32_bf16(af, bfr, acc, 0, 0, 0);
    }
    const int mout = mt * 64 + wave * 16 + quad * 4;
#pragma unroll
    for (int r = 0; r < 4; ++r)
        atomicAdd(&t[(size_t)(mout + r) * RANK + fr], acc[r]);
}

// ---------------------------------------------------------------------------
// Kernel 3 (u8 path): byte-isomorphic to the proven legacy gemm_kernel.
// ONLY change: the 8 per-step q loads are uint32 (4 u8 cols) instead of int4
// (4 int32 cols) at the SAME logical coordinates, and dequant unpacks bytes.
// Scales, swizzle, pipeline, barriers all identical to the proven kernel.
// ---------------------------------------------------------------------------
#define GEMM_STEP_U(KT, P, CUR, NXT)                                           \
    {                                                                          \
        const int ktn = ((KT) + 2) & (NK - 1);                                 \
        _Pragma("unroll")                                                      \
        for (int j = 0; j < 8; ++j) {                                          \
            const int row = qrow + 16 * j;                                     \
            qv[(P) ^ 1][j] = *(const uint32_t*)(qbase + (size_t)row * IN_F + ktn * BK); \
            sc[(P) ^ 1][j] = scales[(size_t)(n0 + row) * SCB + ktn * 2 + qhi]; \
        }                                                                      \
        const int kta = ((KT) + 1) & (NK - 1);                                 \
        _Pragma("unroll")                                                      \
        for (int i = 0; i < 4; ++i) {                                          \
            __builtin_amdgcn_global_load_lds(                                  \
                (const __attribute__((address_space(1))) uint32_t*)(xsrc + (size_t)kta * BK + (size_t)i * 8 * IN_F), \
                (__attribute__((address_space(3))) uint32_t*)(&xs[NXT][(wave * 32 + i * 8) * BK]), \
                16, 0, 0);                                                     \
        }                                                                      \
        _Pragma("unroll")                                                      \
        for (int j = 0; j < 8; ++j) {                                          \
            const float s = sc[P][j];                                          \
            const float c = -128.f * s;                                        \
            const uint32_t qq = qv[P][j];                                      \
            uint2 pk;                                                          \
            pk.x = pack_bf16(fmaf((float)(qq & 0xffu), s, c),                  \
                             fmaf((float)((qq >> 8) & 0xffu), s, c));          \
            pk.y = pack_bf16(fmaf((float)((qq >> 16) & 0xffu), s, c),          \
                             fmaf((float)(qq >> 24), s, c));                   \
            *(uint2*)(&wt[NXT][(qrow + 16 * j) * BK + wpos]) = pk;             \
        }                                                                      \
        _Pragma("unroll")                                                      \
        for (int kk = 0; kk < BK; kk += 32) {                                  \
            bf16x8 af[4], bfr[4];                                              \
            const int pp = (((kk >> 3) + quad) ^ (fr & 7)) * 8;                \
            _Pragma("unroll")                                                  \
            for (int i = 0; i < 4; ++i)                                        \
                af[i] = *(const bf16x8*)(&xs[CUR][(wm * 64 + i * 16 + fr) * BK + pp]); \
            _Pragma("unroll")                                                  \
            for (int j = 0; j < 4; ++j)                                        \
                bfr[j] = *(const bf16x8*)(&wt[CUR][(wn * 64 + j * 16 + fr) * BK + pp]); \
            _Pragma("unroll")                                                  \
            for (int i = 0; i < 4; ++i)                                        \
                _Pragma("unroll")                                              \
                for (int j = 0; j < 4; ++j)                                    \
                    acc[i][j] = __builtin_amdgcn_mfma_f32_16x16x32_bf16(af[i], bfr[j], acc[i][j], 0, 0, 0); \
        }                                                                      \
        __syncthreads();                                                       \
    }

__global__ __launch_bounds__(256, 2) void gemm_u8_kernel(
    const uint16_t* __restrict__ xb,    // bf16 x  [1024][8192] (in ws)
    const uint8_t*  __restrict__ qu8,   // u8      [8192][8192] (in ws)
    const float*    __restrict__ scales,// fp32    [8192][256]
    const float*    __restrict__ t,     // fp32    [1024][16]   (in ws)
    const float*    __restrict__ loraB, // fp32    [8192][16]
    const float*    __restrict__ bias,  // fp32    [8192]
    float*          __restrict__ out)   // fp32    [1024][8192]
{
    __shared__ __align__(16) uint16_t xs[2][BM * BK];   // 2 x 16 KB, swizzled A tiles
    __shared__ __align__(16) uint16_t wt[2][BN * BK];   // 2 x 16 KB, swizzled W tiles

    const int bx    = blockIdx.x;
    const int mtile = bx >> 6;          // proven ordering (same as 607us kernel)
    const int ntile = bx & 63;
    const int m0 = mtile * BM;
    const int n0 = ntile * BN;

    const int tid  = threadIdx.x;
    const int wave = tid >> 6;
    const int lane = tid & 63;
    const int wm = wave & 1, wn = wave >> 1;   // 64x64 wave subtile
    const int fr = lane & 15;
    const int quad = lane >> 4;

    // q staging map over the 128x64 tile: thread t -> row (t>>4)+16j, cols (t&15)*4..+3
    const int qrow  = tid >> 4;
    const int qcol4 = (tid & 15) * 4;
    const int qhi   = (tid >> 3) & 1;
    // swizzled wt write position (constant across j since 16j % 8 == 0)
    const int wpos = ((((tid >> 1) & 7) ^ (qrow & 7)) * 8) + (tid & 1) * 4;

    const uint8_t* qbase = qu8 + (size_t)n0 * IN_F + qcol4;   // byte units

    f32x4 acc[4][4];
    const f32x4 z = {0.f, 0.f, 0.f, 0.f};
#pragma unroll
    for (int i = 0; i < 4; ++i)
#pragma unroll
        for (int j = 0; j < 4; ++j) acc[i][j] = z;

    uint32_t qv[2][8];
    float    sc[2][8];

    // ---- prefetch q for kt=0 (covered by the LoRA prologue)
#pragma unroll
    for (int j = 0; j < 8; ++j) {
        const int row = qrow + 16 * j;
        qv[0][j] = *(const uint32_t*)(qbase + (size_t)row * IN_F);
        sc[0][j] = scales[(size_t)(n0 + row) * SCB + qhi];
    }

    // ---- LoRA as one K=32 MFMA step: A'=t[m][r], B'=2*loraB[o][r], zero-padded.
    // Both tiles stored in the swizzled layout (chunk c of row r at slot c^(r&7)).
    {
        if (tid < 128) {
            const int row = tid, s = row & 7;
            const float4* tp = (const float4*)(t + (size_t)(m0 + row) * RANK);
            const float4 v0 = tp[0], v1 = tp[1], v2 = tp[2], v3 = tp[3];
            uint32_t vals[8];
            vals[0] = pack_bf16(v0.x, v0.y); vals[1] = pack_bf16(v0.z, v0.w);
            vals[2] = pack_bf16(v1.x, v1.y); vals[3] = pack_bf16(v1.z, v1.w);
            vals[4] = pack_bf16(v2.x, v2.y); vals[5] = pack_bf16(v2.z, v2.w);
            vals[6] = pack_bf16(v3.x, v3.y); vals[7] = pack_bf16(v3.z, v3.w);
            uint32_t* dst = (uint32_t*)(&xs[0][row * BK]);
#pragma unroll
            for (int c = 0; c < 8; ++c) {
                const int p = (c ^ s) * 4;
                if (c < 2) {
                    dst[p + 0] = vals[c * 4 + 0]; dst[p + 1] = vals[c * 4 + 1];
                    dst[p + 2] = vals[c * 4 + 2]; dst[p + 3] = vals[c * 4 + 3];
                } else {
                    dst[p + 0] = 0; dst[p + 1] = 0; dst[p + 2] = 0; dst[p + 3] = 0;
                }
            }
        } else {
            const int row = tid - 128, s = row & 7;
            const float4* bp = (const float4*)(loraB + (size_t)(n0 + row) * RANK);
            const float4 v0 = bp[0], v1 = bp[1], v2 = bp[2], v3 = bp[3];
            uint32_t vals[8];
            vals[0] = pack_bf16(2.f * v0.x, 2.f * v0.y); vals[1] = pack_bf16(2.f * v0.z, 2.f * v0.w);
            vals[2] = pack_bf16(2.f * v1.x, 2.f * v1.y); vals[3] = pack_bf16(2.f * v1.z, 2.f * v1.w);
            vals[4] = pack_bf16(2.f * v2.x, 2.f * v2.y); vals[5] = pack_bf16(2.f * v2.z, 2.f * v2.w);
            vals[6] = pack_bf16(2.f * v3.x, 2.f * v3.y); vals[7] = pack_bf16(2.f * v3.z, 2.f * v3.w);
            uint32_t* dst = (uint32_t*)(&wt[0][row * BK]);
#pragma unroll
            for (int c = 0; c < 8; ++c) {
                const int p = (c ^ s) * 4;
                if (c < 2) {
                    dst[p + 0] = vals[c * 4 + 0]; dst[p + 1] = vals[c * 4 + 1];
                    dst[p + 2] = vals[c * 4 + 2]; dst[p + 3] = vals[c * 4 + 3];
                } else {
                    dst[p + 0] = 0; dst[p + 1] = 0; dst[p + 2] = 0; dst[p + 3] = 0;
                }
            }
        }
        __syncthreads();
        const int pp = (quad ^ (fr & 7)) * 8;    // chunk=quad; quads 2,3 read zeros
        bf16x8 af[4], bfr[4];
#pragma unroll
        for (int i = 0; i < 4; ++i)
            af[i] = *(const bf16x8*)(&xs[0][(wm * 64 + i * 16 + fr) * BK + pp]);
#pragma unroll
        for (int j = 0; j < 4; ++j)
            bfr[j] = *(const bf16x8*)(&wt[0][(wn * 64 + j * 16 + fr) * BK + pp]);
#pragma unroll
        for (int i = 0; i < 4; ++i)
#pragma unroll
            for (int j = 0; j < 4; ++j)
                acc[i][j] = __builtin_amdgcn_mfma_f32_16x16x32_bf16(af[i], bfr[j], acc[i][j], 0, 0, 0);
        __syncthreads();   // LoRA reads done before buffers are restaged
    }

    // xs staging map: lane l stages row wave*32+i*8+(l>>3), global chunk
    // (l&7)^(l>>3), landing at LDS slot l&7 (swizzle realized via global perm).
    const int xrow   = wave * 32 + (lane >> 3);
    const int xchunk = (lane & 7) ^ (lane >> 3);
    const uint16_t* xsrc = xb + (size_t)(m0 + xrow) * IN_F + xchunk * 8;

    // ---- pipeline prologue: stage kt=0 into buffer 0, prefetch q for kt=1
#pragma unroll
    for (int i = 0; i < 4; ++i) {
        __builtin_amdgcn_global_load_lds(
            (const __attribute__((address_space(1))) uint32_t*)(xsrc + (size_t)i * 8 * IN_F),
            (__attribute__((address_space(3))) uint32_t*)(&xs[0][(wave * 32 + i * 8) * BK]),
            16, 0, 0);
    }
#pragma unroll
    for (int j = 0; j < 8; ++j) {
        const float s = sc[0][j];
        const float c = -128.f * s;
        const uint32_t qq = qv[0][j];
        uint2 pk;
        pk.x = pack_bf16(fmaf((float)(qq & 0xffu), s, c),
                         fmaf((float)((qq >> 8) & 0xffu), s, c));
        pk.y = pack_bf16(fmaf((float)((qq >> 16) & 0xffu), s, c),
                         fmaf((float)(qq >> 24), s, c));
        *(uint2*)(&wt[0][(qrow + 16 * j) * BK + wpos]) = pk;
    }
#pragma unroll
    for (int j = 0; j < 8; ++j) {
        const int row = qrow + 16 * j;
        qv[0][j] = *(const uint32_t*)(qbase + (size_t)row * IN_F + 1 * BK);
        sc[0][j] = scales[(size_t)(n0 + row) * SCB + 2 + qhi];
    }
    __syncthreads();

    // ---- main loop, unrolled by 2 for the qv ping-pong
    for (int kt = 0; kt < NK; kt += 2) {
        GEMM_STEP_U(kt,     0, 0, 1);
        GEMM_STEP_U(kt + 1, 1, 1, 0);
    }

    // epilogue: + bias, store fp32 (C/D map: col=lane&15, row=quad*4+reg)
#pragma unroll
    for (int j = 0; j < 4; ++j) {
        const int col = n0 + wn * 64 + j * 16 + fr;
        const float bv = bias[col];
#pragma unroll
        for (int i = 0; i < 4; ++i) {
            const int rbase = m0 + wm * 64 + i * 16 + quad * 4;
#pragma unroll
            for (int r = 0; r < 4; ++r)
                out[(size_t)(rbase + r) * OUT_F + col] = acc[i][j][r] + bv;
        }
    }
}

// ---------------------------------------------------------------------------
// Kernel 3 (legacy fallback, unchanged proven 607us kernel): used when ws
// can't hold qu8.
// ---------------------------------------------------------------------------
#define GEMM_STEP_L(KT, P, CUR, NXT)                                           \
    {                                                                          \
        const int ktn = ((KT) + 2) & (NK - 1);                                 \
        _Pragma("unroll")                                                      \
        for (int j = 0; j < 8; ++j) {                                          \
            const int row = qrow + 16 * j;                                     \
            qv[(P) ^ 1][j] = *(const int4*)(qbase + (size_t)row * IN_F + ktn * BK); \
            sc[(P) ^ 1][j] = scales[(size_t)(n0 + row) * SCB + ktn * 2 + qhi]; \
        }                                                                      \
        const int kta = ((KT) + 1) & (NK - 1);                                 \
        _Pragma("unroll")                                                      \
        for (int i = 0; i < 4; ++i) {                                          \
            __builtin_amdgcn_global_load_lds(                                  \
                (const __attribute__((address_space(1))) uint32_t*)(xsrc + (size_t)kta * BK + (size_t)i * 8 * IN_F), \
                (__attribute__((address_space(3))) uint32_t*)(&xs[NXT][(wave * 32 + i * 8) * BK]), \
                16, 0, 0);                                                     \
        }                                                                      \
        _Pragma("unroll")                                                      \
        for (int j = 0; j < 8; ++j) {                                          \
            const float s = sc[P][j];                                          \
            const float c = -128.f * s;                                        \
            const int4 qq = qv[P][j];                                          \
            uint2 pk;                                                          \
            pk.x = pack_bf16(fmaf((float)qq.x, s, c), fmaf((float)qq.y, s, c)); \
            pk.y = pack_bf16(fmaf((float)qq.z, s, c), fmaf((float)qq.w, s, c)); \
            *(uint2*)(&wt[NXT][(qrow + 16 * j) * BK + wpos]) = pk;             \
        }                                                                      \
        _Pragma("unroll")                                                      \
        for (int kk = 0; kk < BK; kk += 32) {                                  \
            bf16x8 af[4], bfr[4];                                              \
            const int pp = (((kk >> 3) + quad) ^ (fr & 7)) * 8;                \
            _Pragma("unroll")                                                  \
            for (int i = 0; i < 4; ++i)                                        \
                af[i] = *(const bf16x8*)(&xs[CUR][(wm * 64 + i * 16 + fr) * BK + pp]); \
            _Pragma("unroll")                                                  \
            for (int j = 0; j < 4; ++j)                                        \
                bfr[j] = *(const bf16x8*)(&wt[CUR][(wn * 64 + j * 16 + fr) * BK + pp]); \
            _Pragma("unroll")                                                  \
            for (int i = 0; i < 4; ++i)                                        \
                _Pragma("unroll")                                              \
                for (int j = 0; j < 4; ++j)                                    \
                    acc[i][j] = __builtin_amdgcn_mfma_f32_16x16x32_bf16(af[i], bfr[j], acc[i][j], 0, 0, 0); \
        }                                                                      \
        __syncthreads();                                                       \
    }

__global__ __launch_bounds__(256, 2) void gemm_kernel(
    const uint16_t* __restrict__ xb,
    const int*      __restrict__ q,
    const float*    __restrict__ scales,
    const float*    __restrict__ t,
    const float*    __restrict__ loraB,
    const float*    __restrict__ bias,
    float*          __restrict__ out)
{
    __shared__ __align__(16) uint16_t xs[2][BM * BK];
    __shared__ __align__(16) uint16_t wt[2][BN * BK];

    const int bx    = blockIdx.x;
    const int mtile = bx >> 6;
    const int ntile = bx & 63;
    const int m0 = mtile * BM;
    const int n0 = ntile * BN;

    const int tid  = threadIdx.x;
    const int wave = tid >> 6;
    const int lane = tid & 63;
    const int wm = wave & 1, wn = wave >> 1;
    const int fr = lane & 15;
    const int quad = lane >> 4;

    const int qrow  = tid >> 4;
    const int qcol4 = (tid & 15) * 4;
    const int qhi   = (tid >> 3) & 1;
    const int wpos = ((((tid >> 1) & 7) ^ (qrow & 7)) * 8) + (tid & 1) * 4;

    const int* qbase = q + (size_t)n0 * IN_F + qcol4;

    f32x4 acc[4][4];
    const f32x4 z = {0.f, 0.f, 0.f, 0.f};
#pragma unroll
    for (int i = 0; i < 4; ++i)
#pragma unroll
        for (int j = 0; j < 4; ++j) acc[i][j] = z;

    int4  qv[2][8];
    float sc[2][8];

#pragma unroll
    for (int j = 0; j < 8; ++j) {
        const int row = qrow + 16 * j;
        qv[0][j] = *(const int4*)(qbase + (size_t)row * IN_F);
        sc[0][j] = scales[(size_t)(n0 + row) * SCB + qhi];
    }

    {
        if (tid < 128) {
            const int row = tid, s = row & 7;
            const float4* tp = (const float4*)(t + (size_t)(m0 + row) * RANK);
            const float4 v0 = tp[0], v1 = tp[1], v2 = tp[2], v3 = tp[3];
            uint32_t vals[8];
            vals[0] = pack_bf16(v0.x, v0.y); vals[1] = pack_bf16(v0.z, v0.w);
            vals[2] = pack_bf16(v1.x, v1.y); vals[3] = pack_bf16(v1.z, v1.w);
            vals[4] = pack_bf16(v2.x, v2.y); vals[5] = pack_bf16(v2.z, v2.w);
            vals[6] = pack_bf16(v3.x, v3.y); vals[7] = pack_bf16(v3.z, v3.w);
            uint32_t* dst = (uint32_t*)(&xs[0][row * BK]);
#pragma unroll
            for (int c = 0; c < 8; ++c) {
                const int p = (c ^ s) * 4;
                if (c < 2) {
                    dst[p + 0] = vals[c * 4 + 0]; dst[p + 1] = vals[c * 4 + 1];
                    dst[p + 2] = vals[c * 4 + 2]; dst[p + 3] = vals[c * 4 + 3];
                } else {
                    dst[p + 0] = 0; dst[p + 1] = 0; dst[p + 2] = 0; dst[p + 3] = 0;
                }
            }
        } else {
            const int row = tid - 128, s = row & 7;
            const float4* bp = (const float4*)(loraB + (size_t)(n0 + row) * RANK);
            const float4 v0 = bp[0], v1 = bp[1], v2 = bp[2], v3 = bp[3];
            uint32_t vals[8];
            vals[0] = pack_bf16(2.f * v0.x, 2.f * v0.y); vals[1] = pack_bf16(2.f * v0.z, 2.f * v0.w);
            vals[2] = pack_bf16(2.f * v1.x, 2.f * v1.y); vals[3] = pack_bf16(2.f * v1.z, 2.f * v1.w);
            vals[4] = pack_bf16(2.f * v2.x, 2.f * v2.y); vals[5] = pack_bf16(2.f * v2.z, 2.f * v2.w);
            vals[6] = pack_bf16(2.f * v3.x, 2.f * v3.y); vals[7] = pack_bf16(2.f * v3.z, 2.f * v3.w);
            uint32_t* dst = (uint32_t*)(&wt[0][row * BK]);
#pragma unroll
            for (int c = 0; c < 8; ++c) {
                const int p = (c ^ s) * 4;
                if (c < 2) {
                    dst[p + 0] = vals[c * 4 + 0]; dst[p + 1] = vals[c * 4 + 1];
                    dst[p + 2] = vals[c * 4 + 2]; dst[p + 3] = vals[c * 4 + 3];
                } else {
                    dst[p + 0] = 0; dst[p + 1] = 0; dst[p + 2] = 0; dst[p + 3] = 0;
                }
            }
        }
        __syncthreads();
        const int pp = (quad ^ (fr & 7)) * 8;
        bf16x8 af[4], bfr[4];
#pragma unroll
        for (int i = 0; i < 4; ++i)
            af[i] = *(const bf16x8*)(&xs[0][(wm * 64 + i * 16 + fr) * BK + pp]);
#pragma unroll
        for (int j = 0; j < 4; ++j)
            bfr[j] = *(const bf16x8*)(&wt[0][(wn * 64 + j * 16 + fr) * BK + pp]);
#pragma unroll
        for (int i = 0; i < 4; ++i)
#pragma unroll
            for (int j = 0; j < 4; ++j)
                acc[i][j] = __builtin_amdgcn_mfma_f32_16x16x32_bf16(af[i], bfr[j], acc[i][j], 0, 0, 0);
        __syncthreads();
    }

    const int xrow   = wave * 32 + (lane >> 3);
    const int xchunk = (lane & 7) ^ (lane >> 3);
    const uint16_t* xsrc = xb + (size_t)(m0 + xrow) * IN_F + xchunk * 8;

#pragma unroll
    for (int i = 0; i < 4; ++i) {
        __builtin_amdgcn_global_load_lds(
            (const __attribute__((address_space(1))) uint32_t*)(xsrc + (size_t)i * 8 * IN_F),
            (__attribute__((address_space(3))) uint32_t*)(&xs[0][(wave * 32 + i * 8) * BK]),
            16, 0, 0);
    }
#pragma unroll
    for (int j = 0; j < 8; ++j) {
        const float s = sc[0][j];
        const float c = -128.f * s;
        const int4 qq = qv[0][j];
        uint2 pk;
        pk.x = pack_bf16(fmaf((float)qq.x, s, c), fmaf((float)qq.y, s, c));
        pk.y = pack_bf16(fmaf((float)qq.z, s, c), fmaf((float)qq.w, s, c));
        *(uint2*)(&wt[0][(qrow + 16 * j) * BK + wpos]) = pk;
    }
#pragma unroll
    for (int j = 0; j < 8; ++j) {
        const int row = qrow + 16 * j;
        qv[0][j] = *(const int4*)(qbase + (size_t)row * IN_F + 1 * BK);
        sc[0][j] = scales[(size_t)(n0 + row) * SCB + 2 + qhi];
    }
    __syncthreads();

    for (int kt = 0; kt < NK; kt += 2) {
        GEMM_STEP_L(kt,     0, 0, 1);
        GEMM_STEP_L(kt + 1, 1, 1, 0);
    }

#pragma unroll
    for (int j = 0; j < 4; ++j) {
        const int col = n0 + wn * 64 + j * 16 + fr;
        const float bv = bias[col];
#pragma unroll
        for (int i = 0; i < 4; ++i) {
            const int rbase = m0 + wm * 64 + i * 16 + quad * 4;
#pragma unroll
            for (int r = 0; r < 4; ++r)
                out[(size_t)(rbase + r) * OUT_F + col] = acc[i][j][r] + bv;
        }
    }
}

extern "C" void kernel_launch(void* const* d_in, const int* in_sizes, int n_in,
                              void* d_out, int out_size, void* d_ws, size_t ws_size,
                              hipStream_t stream) {
    const float* x      = (const float*)d_in[0];
    const int*   q      = (const int*)d_in[1];
    const float* scales = (const float*)d_in[2];
    const float* lora_A = (const float*)d_in[3];
    const float* lora_B = (const float*)d_in[4];
    const float* bias   = (const float*)d_in[5];
    float* out = (float*)d_out;

    // ws layout: [0,16MB) xb bf16[1024][8192]; t fp32[1024][16]; then qu8
    const size_t xb_bytes = (size_t)M_TOT * IN_F * sizeof(uint16_t);   // 16 MB
    const size_t t_bytes  = (size_t)M_TOT * RANK * sizeof(float);      // 64 KB
    const size_t q8_off   = xb_bytes + t_bytes;                        // 16B-aligned
    const size_t q8_bytes = (size_t)OUT_F * IN_F;                      // 64 MB

    uint16_t* xb = (uint16_t*)d_ws;
    float*    t  = (float*)((char*)d_ws + xb_bytes);

    if (ws_size >= q8_off + q8_bytes) {
        uint8_t* qu8 = (uint8_t*)d_ws + q8_off;
        narrow_kernel<<<(OUT_F / 256) * (IN_F / 16), 256, 0, stream>>>(q, qu8);
        convert_kernel<<<M_TOT, 256, 0, stream>>>(x, (uint2*)xb, t);   // also zeroes t
        lora_t_kernel<<<256, 256, 0, stream>>>(x, lora_A, t);
        gemm_u8_kernel<<<(M_TOT / BM) * (OUT_F / BN), 256, 0, stream>>>(
            xb, qu8, scales, t, lora_B, bias, out);
    } else {
        convert_kernel<<<M_TOT, 256, 0, stream>>>(x, (uint2*)xb, t);   // also zeroes t
        lora_t_kernel<<<256, 256, 0, stream>>>(x, lora_A, t);
        gemm_kernel<<<(M_TOT / BM) * (OUT_F / BN), 256, 0, stream>>>(
            xb, q, scales, t, lora_B, bias, out);
    }
}

// Round 3
// 602.731 us; speedup vs baseline: 1.0075x; 1.0075x over previous
//
#include <hip/hip_runtime.h>
#include <hip/hip_bf16.h>
#include <stdint.h>

#define OUT_F 8192
#define IN_F  8192
#define RANK  16
#define M_TOT 1024   // B*S
#define BM 128
#define BN 128
#define BK 64
#define NK (IN_F / BK)   // 128
#define SCB (IN_F / 32)  // 256 scale blocks per weight row

typedef __bf16 bf16x8 __attribute__((ext_vector_type(8)));
typedef float  f32x4  __attribute__((ext_vector_type(4)));

// round-half-up f32->bf16 pack of two floats into one uint32 (lo in low half)
static __device__ __forceinline__ uint32_t pack_bf16(float lo, float hi) {
    uint32_t a = __builtin_bit_cast(uint32_t, lo);
    uint32_t b = __builtin_bit_cast(uint32_t, hi);
    return ((a + 0x8000u) >> 16) | ((b + 0x8000u) & 0xffff0000u);
}

// ---------------------------------------------------------------------------
// Kernel 1 (fused prep): one streaming pass doing
//   - t zero (first 16384 threads)
//   - x fp32 -> bf16 into xb (48 MB traffic)
//   - q int32 -> u8 narrow into qu8, IDENTICAL [o][i] layout (320 MB traffic)
// All loads lane-contiguous (16 B/lane int4 reads -> 1 KB/wave/instr).
// ---------------------------------------------------------------------------
__global__ __launch_bounds__(256) void prep_kernel(
    const float* __restrict__ x, const int* __restrict__ q,
    uint2* __restrict__ xb2, uint32_t* __restrict__ qu32,
    float* __restrict__ t)
{
    const int gid = blockIdx.x * 256 + threadIdx.x;   // 0..524287 (2048 blocks)
    if (gid < M_TOT * RANK) t[gid] = 0.f;

    // x: 2M float4, 4 per thread, grid-strided (coalesced)
    const float4* x4 = (const float4*)x;
#pragma unroll
    for (int j = 0; j < 4; ++j) {
        const int i = gid + j * 524288;
        const float4 v = x4[i];
        uint2 p;
        p.x = pack_bf16(v.x, v.y);
        p.y = pack_bf16(v.z, v.w);
        xb2[i] = p;
    }

    // q: 16M int4 chunks (64M ints), 32 per thread, grid-strided (coalesced)
    const int4* q4 = (const int4*)q;
#pragma unroll 8
    for (int k = 0; k < 32; ++k) {
        const size_t i = (size_t)gid + (size_t)k * 524288;
        const int4 a = q4[i];
        qu32[i] = (uint32_t)a.x | ((uint32_t)a.y << 8) |
                  ((uint32_t)a.z << 16) | ((uint32_t)a.w << 24);
    }
}

// ---------------------------------------------------------------------------
// Kernel 1f (fallback prep when ws can't hold qu8): x convert + t zero only.
// ---------------------------------------------------------------------------
__global__ __launch_bounds__(256) void convert_kernel(
    const float* __restrict__ x, uint2* __restrict__ xb2, float* __restrict__ t)
{
    const int tid = threadIdx.x, b = blockIdx.x;
    if (b < 64) t[b * 256 + tid] = 0.f;
    const float4* x4 = (const float4*)x;
    const int base = b * 256 + tid;
#pragma unroll
    for (int j = 0; j < 8; ++j) {
        const int i = base + j * 262144;       // 2M float4 total
        const float4 v = x4[i];
        uint2 p;
        p.x = pack_bf16(v.x, v.y);
        p.y = pack_bf16(v.z, v.w);
        xb2[i] = p;
    }
}

// ---------------------------------------------------------------------------
// Kernel 2: t = x @ lora_A^T via MFMA split-K + atomicAdd.
// Restructured: split-k 64 (1024 blocks -> 4 blocks/CU, 16 waves/CU) and
// reads xb (bf16 packed by prep, bit-identical values) -> no x-side pack
// VALU, half the x bytes. lora_A rows are L2-hot across blocks.
// ---------------------------------------------------------------------------
__global__ __launch_bounds__(256) void lora_t_kernel(
    const uint16_t* __restrict__ xb, const float* __restrict__ lora_A,
    float* __restrict__ t)
{
    const int b = blockIdx.x;           // 1024 blocks
    const int mt = b >> 6, ks = b & 63;
    const int tid = threadIdx.x, wave = tid >> 6, lane = tid & 63;
    const int fr = lane & 15, quad = lane >> 4;
    const int m = mt * 64 + wave * 16 + fr;
    const int k0 = ks * 128 + quad * 8;

    f32x4 acc = {0.f, 0.f, 0.f, 0.f};
    const uint16_t* xr = xb + (size_t)m * IN_F + k0;
    const float* ar = lora_A + (size_t)fr * IN_F + k0;

#pragma unroll
    for (int s = 0; s < 4; ++s) {
        const bf16x8 af = *(const bf16x8*)(xr + s * 32);
        const float4 a0 = *(const float4*)(ar + s * 32);
        const float4 a1 = *(const float4*)(ar + s * 32 + 4);
        bf16x8 bfr;
        uint32_t* bp = (uint32_t*)&bfr;
        bp[0] = pack_bf16(a0.x, a0.y); bp[1] = pack_bf16(a0.z, a0.w);
        bp[2] = pack_bf16(a1.x, a1.y); bp[3] = pack_bf16(a1.z, a1.w);
        acc = __builtin_amdgcn_mfma_f32_16x16x32_bf16(af, bfr, acc, 0, 0, 0);
    }
    const int mout = mt * 64 + wave * 16 + quad * 4;
#pragma unroll
    for (int r = 0; r < 4; ++r)
        atomicAdd(&t[(size_t)(mout + r) * RANK + fr], acc[r]);
}

// ---------------------------------------------------------------------------
// Kernel 3 (u8 path, UNCHANGED from the passing 217us round-2 kernel).
// ---------------------------------------------------------------------------
#define GEMM_STEP_U(KT, P, CUR, NXT)                                           \
    {                                                                          \
        const int ktn = ((KT) + 2) & (NK - 1);                                 \
        _Pragma("unroll")                                                      \
        for (int j = 0; j < 8; ++j) {                                          \
            const int row = qrow + 16 * j;                                     \
            qv[(P) ^ 1][j] = *(const uint32_t*)(qbase + (size_t)row * IN_F + ktn * BK); \
            sc[(P) ^ 1][j] = scales[(size_t)(n0 + row) * SCB + ktn * 2 + qhi]; \
        }                                                                      \
        const int kta = ((KT) + 1) & (NK - 1);                                 \
        _Pragma("unroll")                                                      \
        for (int i = 0; i < 4; ++i) {                                          \
            __builtin_amdgcn_global_load_lds(                                  \
                (const __attribute__((address_space(1))) uint32_t*)(xsrc + (size_t)kta * BK + (size_t)i * 8 * IN_F), \
                (__attribute__((address_space(3))) uint32_t*)(&xs[NXT][(wave * 32 + i * 8) * BK]), \
                16, 0, 0);                                                     \
        }                                                                      \
        _Pragma("unroll")                                                      \
        for (int j = 0; j < 8; ++j) {                                          \
            const float s = sc[P][j];                                          \
            const float c = -128.f * s;                                        \
            const uint32_t qq = qv[P][j];                                      \
            uint2 pk;                                                          \
            pk.x = pack_bf16(fmaf((float)(qq & 0xffu), s, c),                  \
                             fmaf((float)((qq >> 8) & 0xffu), s, c));          \
            pk.y = pack_bf16(fmaf((float)((qq >> 16) & 0xffu), s, c),          \
                             fmaf((float)(qq >> 24), s, c));                   \
            *(uint2*)(&wt[NXT][(qrow + 16 * j) * BK + wpos]) = pk;             \
        }                                                                      \
        _Pragma("unroll")                                                      \
        for (int kk = 0; kk < BK; kk += 32) {                                  \
            bf16x8 af[4], bfr[4];                                              \
            const int pp = (((kk >> 3) + quad) ^ (fr & 7)) * 8;                \
            _Pragma("unroll")                                                  \
            for (int i = 0; i < 4; ++i)                                        \
                af[i] = *(const bf16x8*)(&xs[CUR][(wm * 64 + i * 16 + fr) * BK + pp]); \
            _Pragma("unroll")                                                  \
            for (int j = 0; j < 4; ++j)                                        \
                bfr[j] = *(const bf16x8*)(&wt[CUR][(wn * 64 + j * 16 + fr) * BK + pp]); \
            _Pragma("unroll")                                                  \
            for (int i = 0; i < 4; ++i)                                        \
                _Pragma("unroll")                                              \
                for (int j = 0; j < 4; ++j)                                    \
                    acc[i][j] = __builtin_amdgcn_mfma_f32_16x16x32_bf16(af[i], bfr[j], acc[i][j], 0, 0, 0); \
        }                                                                      \
        __syncthreads();                                                       \
    }

__global__ __launch_bounds__(256, 2) void gemm_u8_kernel(
    const uint16_t* __restrict__ xb,    // bf16 x  [1024][8192] (in ws)
    const uint8_t*  __restrict__ qu8,   // u8      [8192][8192] (in ws)
    const float*    __restrict__ scales,// fp32    [8192][256]
    const float*    __restrict__ t,     // fp32    [1024][16]   (in ws)
    const float*    __restrict__ loraB, // fp32    [8192][16]
    const float*    __restrict__ bias,  // fp32    [8192]
    float*          __restrict__ out)   // fp32    [1024][8192]
{
    __shared__ __align__(16) uint16_t xs[2][BM * BK];   // 2 x 16 KB, swizzled A tiles
    __shared__ __align__(16) uint16_t wt[2][BN * BK];   // 2 x 16 KB, swizzled W tiles

    const int bx    = blockIdx.x;
    const int mtile = bx >> 6;          // proven ordering
    const int ntile = bx & 63;
    const int m0 = mtile * BM;
    const int n0 = ntile * BN;

    const int tid  = threadIdx.x;
    const int wave = tid >> 6;
    const int lane = tid & 63;
    const int wm = wave & 1, wn = wave >> 1;   // 64x64 wave subtile
    const int fr = lane & 15;
    const int quad = lane >> 4;

    const int qrow  = tid >> 4;
    const int qcol4 = (tid & 15) * 4;
    const int qhi   = (tid >> 3) & 1;
    const int wpos = ((((tid >> 1) & 7) ^ (qrow & 7)) * 8) + (tid & 1) * 4;

    const uint8_t* qbase = qu8 + (size_t)n0 * IN_F + qcol4;   // byte units

    f32x4 acc[4][4];
    const f32x4 z = {0.f, 0.f, 0.f, 0.f};
#pragma unroll
    for (int i = 0; i < 4; ++i)
#pragma unroll
        for (int j = 0; j < 4; ++j) acc[i][j] = z;

    uint32_t qv[2][8];
    float    sc[2][8];

#pragma unroll
    for (int j = 0; j < 8; ++j) {
        const int row = qrow + 16 * j;
        qv[0][j] = *(const uint32_t*)(qbase + (size_t)row * IN_F);
        sc[0][j] = scales[(size_t)(n0 + row) * SCB + qhi];
    }

    // ---- LoRA as one K=32 MFMA step: A'=t[m][r], B'=2*loraB[o][r], zero-padded.
    {
        if (tid < 128) {
            const int row = tid, s = row & 7;
            const float4* tp = (const float4*)(t + (size_t)(m0 + row) * RANK);
            const float4 v0 = tp[0], v1 = tp[1], v2 = tp[2], v3 = tp[3];
            uint32_t vals[8];
            vals[0] = pack_bf16(v0.x, v0.y); vals[1] = pack_bf16(v0.z, v0.w);
            vals[2] = pack_bf16(v1.x, v1.y); vals[3] = pack_bf16(v1.z, v1.w);
            vals[4] = pack_bf16(v2.x, v2.y); vals[5] = pack_bf16(v2.z, v2.w);
            vals[6] = pack_bf16(v3.x, v3.y); vals[7] = pack_bf16(v3.z, v3.w);
            uint32_t* dst = (uint32_t*)(&xs[0][row * BK]);
#pragma unroll
            for (int c = 0; c < 8; ++c) {
                const int p = (c ^ s) * 4;
                if (c < 2) {
                    dst[p + 0] = vals[c * 4 + 0]; dst[p + 1] = vals[c * 4 + 1];
                    dst[p + 2] = vals[c * 4 + 2]; dst[p + 3] = vals[c * 4 + 3];
                } else {
                    dst[p + 0] = 0; dst[p + 1] = 0; dst[p + 2] = 0; dst[p + 3] = 0;
                }
            }
        } else {
            const int row = tid - 128, s = row & 7;
            const float4* bp = (const float4*)(loraB + (size_t)(n0 + row) * RANK);
            const float4 v0 = bp[0], v1 = bp[1], v2 = bp[2], v3 = bp[3];
            uint32_t vals[8];
            vals[0] = pack_bf16(2.f * v0.x, 2.f * v0.y); vals[1] = pack_bf16(2.f * v0.z, 2.f * v0.w);
            vals[2] = pack_bf16(2.f * v1.x, 2.f * v1.y); vals[3] = pack_bf16(2.f * v1.z, 2.f * v1.w);
            vals[4] = pack_bf16(2.f * v2.x, 2.f * v2.y); vals[5] = pack_bf16(2.f * v2.z, 2.f * v2.w);
            vals[6] = pack_bf16(2.f * v3.x, 2.f * v3.y); vals[7] = pack_bf16(2.f * v3.z, 2.f * v3.w);
            uint32_t* dst = (uint32_t*)(&wt[0][row * BK]);
#pragma unroll
            for (int c = 0; c < 8; ++c) {
                const int p = (c ^ s) * 4;
                if (c < 2) {
                    dst[p + 0] = vals[c * 4 + 0]; dst[p + 1] = vals[c * 4 + 1];
                    dst[p + 2] = vals[c * 4 + 2]; dst[p + 3] = vals[c * 4 + 3];
                } else {
                    dst[p + 0] = 0; dst[p + 1] = 0; dst[p + 2] = 0; dst[p + 3] = 0;
                }
            }
        }
        __syncthreads();
        const int pp = (quad ^ (fr & 7)) * 8;    // chunk=quad; quads 2,3 read zeros
        bf16x8 af[4], bfr[4];
#pragma unroll
        for (int i = 0; i < 4; ++i)
            af[i] = *(const bf16x8*)(&xs[0][(wm * 64 + i * 16 + fr) * BK + pp]);
#pragma unroll
        for (int j = 0; j < 4; ++j)
            bfr[j] = *(const bf16x8*)(&wt[0][(wn * 64 + j * 16 + fr) * BK + pp]);
#pragma unroll
        for (int i = 0; i < 4; ++i)
#pragma unroll
            for (int j = 0; j < 4; ++j)
                acc[i][j] = __builtin_amdgcn_mfma_f32_16x16x32_bf16(af[i], bfr[j], acc[i][j], 0, 0, 0);
        __syncthreads();   // LoRA reads done before buffers are restaged
    }

    const int xrow   = wave * 32 + (lane >> 3);
    const int xchunk = (lane & 7) ^ (lane >> 3);
    const uint16_t* xsrc = xb + (size_t)(m0 + xrow) * IN_F + xchunk * 8;

    // ---- pipeline prologue: stage kt=0 into buffer 0, prefetch q for kt=1
#pragma unroll
    for (int i = 0; i < 4; ++i) {
        __builtin_amdgcn_global_load_lds(
            (const __attribute__((address_space(1))) uint32_t*)(xsrc + (size_t)i * 8 * IN_F),
            (__attribute__((address_space(3))) uint32_t*)(&xs[0][(wave * 32 + i * 8) * BK]),
            16, 0, 0);
    }
#pragma unroll
    for (int j = 0; j < 8; ++j) {
        const float s = sc[0][j];
        const float c = -128.f * s;
        const uint32_t qq = qv[0][j];
        uint2 pk;
        pk.x = pack_bf16(fmaf((float)(qq & 0xffu), s, c),
                         fmaf((float)((qq >> 8) & 0xffu), s, c));
        pk.y = pack_bf16(fmaf((float)((qq >> 16) & 0xffu), s, c),
                         fmaf((float)(qq >> 24), s, c));
        *(uint2*)(&wt[0][(qrow + 16 * j) * BK + wpos]) = pk;
    }
#pragma unroll
    for (int j = 0; j < 8; ++j) {
        const int row = qrow + 16 * j;
        qv[0][j] = *(const uint32_t*)(qbase + (size_t)row * IN_F + 1 * BK);
        sc[0][j] = scales[(size_t)(n0 + row) * SCB + 2 + qhi];
    }
    __syncthreads();

    for (int kt = 0; kt < NK; kt += 2) {
        GEMM_STEP_U(kt,     0, 0, 1);
        GEMM_STEP_U(kt + 1, 1, 1, 0);
    }

    // epilogue: + bias, store fp32 (C/D map: col=lane&15, row=quad*4+reg)
#pragma unroll
    for (int j = 0; j < 4; ++j) {
        const int col = n0 + wn * 64 + j * 16 + fr;
        const float bv = bias[col];
#pragma unroll
        for (int i = 0; i < 4; ++i) {
            const int rbase = m0 + wm * 64 + i * 16 + quad * 4;
#pragma unroll
            for (int r = 0; r < 4; ++r)
                out[(size_t)(rbase + r) * OUT_F + col] = acc[i][j][r] + bv;
        }
    }
}

// ---------------------------------------------------------------------------
// Kernel 3 (legacy fallback, unchanged): used when ws can't hold qu8.
// ---------------------------------------------------------------------------
#define GEMM_STEP_L(KT, P, CUR, NXT)                                           \
    {                                                                          \
        const int ktn = ((KT) + 2) & (NK - 1);                                 \
        _Pragma("unroll")                                                      \
        for (int j = 0; j < 8; ++j) {                                          \
            const int row = qrow + 16 * j;                                     \
            qv[(P) ^ 1][j] = *(const int4*)(qbase + (size_t)row * IN_F + ktn * BK); \
            sc[(P) ^ 1][j] = scales[(size_t)(n0 + row) * SCB + ktn * 2 + qhi]; \
        }                                                                      \
        const int kta = ((KT) + 1) & (NK - 1);                                 \
        _Pragma("unroll")                                                      \
        for (int i = 0; i < 4; ++i) {                                          \
            __builtin_amdgcn_global_load_lds(                                  \
                (const __attribute__((address_space(1))) uint32_t*)(xsrc + (size_t)kta * BK + (size_t)i * 8 * IN_F), \
                (__attribute__((address_space(3))) uint32_t*)(&xs[NXT][(wave * 32 + i * 8) * BK]), \
                16, 0, 0);                                                     \
        }                                                                      \
        _Pragma("unroll")                                                      \
        for (int j = 0; j < 8; ++j) {                                          \
            const float s = sc[P][j];                                          \
            const float c = -128.f * s;                                        \
            const int4 qq = qv[P][j];                                          \
            uint2 pk;                                                          \
            pk.x = pack_bf16(fmaf((float)qq.x, s, c), fmaf((float)qq.y, s, c)); \
            pk.y = pack_bf16(fmaf((float)qq.z, s, c), fmaf((float)qq.w, s, c)); \
            *(uint2*)(&wt[NXT][(qrow + 16 * j) * BK + wpos]) = pk;             \
        }                                                                      \
        _Pragma("unroll")                                                      \
        for (int kk = 0; kk < BK; kk += 32) {                                  \
            bf16x8 af[4], bfr[4];                                              \
            const int pp = (((kk >> 3) + quad) ^ (fr & 7)) * 8;                \
            _Pragma("unroll")                                                  \
            for (int i = 0; i < 4; ++i)                                        \
                af[i] = *(const bf16x8*)(&xs[CUR][(wm * 64 + i * 16 + fr) * BK + pp]); \
            _Pragma("unroll")                                                  \
            for (int j = 0; j < 4; ++j)                                        \
                bfr[j] = *(const bf16x8*)(&wt[CUR][(wn * 64 + j * 16 + fr) * BK + pp]); \
            _Pragma("unroll")                                                  \
            for (int i = 0; i < 4; ++i)                                        \
                _Pragma("unroll")                                              \
                for (int j = 0; j < 4; ++j)                                    \
                    acc[i][j] = __builtin_amdgcn_mfma_f32_16x16x32_bf16(af[i], bfr[j], acc[i][j], 0, 0, 0); \
        }                                                                      \
        __syncthreads();                                                       \
    }

__global__ __launch_bounds__(256, 2) void gemm_kernel(
    const uint16_t* __restrict__ xb,
    const int*      __restrict__ q,
    const float*    __restrict__ scales,
    const float*    __restrict__ t,
    const float*    __restrict__ loraB,
    const float*    __restrict__ bias,
    float*          __restrict__ out)
{
    __shared__ __align__(16) uint16_t xs[2][BM * BK];
    __shared__ __align__(16) uint16_t wt[2][BN * BK];

    const int bx    = blockIdx.x;
    const int mtile = bx >> 6;
    const int ntile = bx & 63;
    const int m0 = mtile * BM;
    const int n0 = ntile * BN;

    const int tid  = threadIdx.x;
    const int wave = tid >> 6;
    const int lane = tid & 63;
    const int wm = wave & 1, wn = wave >> 1;
    const int fr = lane & 15;
    const int quad = lane >> 4;

    const int qrow  = tid >> 4;
    const int qcol4 = (tid & 15) * 4;
    const int qhi   = (tid >> 3) & 1;
    const int wpos = ((((tid >> 1) & 7) ^ (qrow & 7)) * 8) + (tid & 1) * 4;

    const int* qbase = q + (size_t)n0 * IN_F + qcol4;

    f32x4 acc[4][4];
    const f32x4 z = {0.f, 0.f, 0.f, 0.f};
#pragma unroll
    for (int i = 0; i < 4; ++i)
#pragma unroll
        for (int j = 0; j < 4; ++j) acc[i][j] = z;

    int4  qv[2][8];
    float sc[2][8];

#pragma unroll
    for (int j = 0; j < 8; ++j) {
        const int row = qrow + 16 * j;
        qv[0][j] = *(const int4*)(qbase + (size_t)row * IN_F);
        sc[0][j] = scales[(size_t)(n0 + row) * SCB + qhi];
    }

    {
        if (tid < 128) {
            const int row = tid, s = row & 7;
            const float4* tp = (const float4*)(t + (size_t)(m0 + row) * RANK);
            const float4 v0 = tp[0], v1 = tp[1], v2 = tp[2], v3 = tp[3];
            uint32_t vals[8];
            vals[0] = pack_bf16(v0.x, v0.y); vals[1] = pack_bf16(v0.z, v0.w);
            vals[2] = pack_bf16(v1.x, v1.y); vals[3] = pack_bf16(v1.z, v1.w);
            vals[4] = pack_bf16(v2.x, v2.y); vals[5] = pack_bf16(v2.z, v2.w);
            vals[6] = pack_bf16(v3.x, v3.y); vals[7] = pack_bf16(v3.z, v3.w);
            uint32_t* dst = (uint32_t*)(&xs[0][row * BK]);
#pragma unroll
            for (int c = 0; c < 8; ++c) {
                const int p = (c ^ s) * 4;
                if (c < 2) {
                    dst[p + 0] = vals[c * 4 + 0]; dst[p + 1] = vals[c * 4 + 1];
                    dst[p + 2] = vals[c * 4 + 2]; dst[p + 3] = vals[c * 4 + 3];
                } else {
                    dst[p + 0] = 0; dst[p + 1] = 0; dst[p + 2] = 0; dst[p + 3] = 0;
                }
            }
        } else {
            const int row = tid - 128, s = row & 7;
            const float4* bp = (const float4*)(loraB + (size_t)(n0 + row) * RANK);
            const float4 v0 = bp[0], v1 = bp[1], v2 = bp[2], v3 = bp[3];
            uint32_t vals[8];
            vals[0] = pack_bf16(2.f * v0.x, 2.f * v0.y); vals[1] = pack_bf16(2.f * v0.z, 2.f * v0.w);
            vals[2] = pack_bf16(2.f * v1.x, 2.f * v1.y); vals[3] = pack_bf16(2.f * v1.z, 2.f * v1.w);
            vals[4] = pack_bf16(2.f * v2.x, 2.f * v2.y); vals[5] = pack_bf16(2.f * v2.z, 2.f * v2.w);
            vals[6] = pack_bf16(2.f * v3.x, 2.f * v3.y); vals[7] = pack_bf16(2.f * v3.z, 2.f * v3.w);
            uint32_t* dst = (uint32_t*)(&wt[0][row * BK]);
#pragma unroll
            for (int c = 0; c < 8; ++c) {
                const int p = (c ^ s) * 4;
                if (c < 2) {
                    dst[p + 0] = vals[c * 4 + 0]; dst[p + 1] = vals[c * 4 + 1];
                    dst[p + 2] = vals[c * 4 + 2]; dst[p + 3] = vals[c * 4 + 3];
                } else {
                    dst[p + 0] = 0; dst[p + 1] = 0; dst[p + 2] = 0; dst[p + 3] = 0;
                }
            }
        }
        __syncthreads();
        const int pp = (quad ^ (fr & 7)) * 8;
        bf16x8 af[4], bfr[4];
#pragma unroll
        for (int i = 0; i < 4; ++i)
            af[i] = *(const bf16x8*)(&xs[0][(wm * 64 + i * 16 + fr) * BK + pp]);
#pragma unroll
        for (int j = 0; j < 4; ++j)
            bfr[j] = *(const bf16x8*)(&wt[0][(wn * 64 + j * 16 + fr) * BK + pp]);
#pragma unroll
        for (int i = 0; i < 4; ++i)
#pragma unroll
            for (int j = 0; j < 4; ++j)
                acc[i][j] = __builtin_amdgcn_mfma_f32_16x16x32_bf16(af[i], bfr[j], acc[i][j], 0, 0, 0);
        __syncthreads();
    }

    const int xrow   = wave * 32 + (lane >> 3);
    const int xchunk = (lane & 7) ^ (lane >> 3);
    const uint16_t* xsrc = xb + (size_t)(m0 + xrow) * IN_F + xchunk * 8;

#pragma unroll
    for (int i = 0; i < 4; ++i) {
        __builtin_amdgcn_global_load_lds(
            (const __attribute__((address_space(1))) uint32_t*)(xsrc + (size_t)i * 8 * IN_F),
            (__attribute__((address_space(3))) uint32_t*)(&xs[0][(wave * 32 + i * 8) * BK]),
            16, 0, 0);
    }
#pragma unroll
    for (int j = 0; j < 8; ++j) {
        const float s = sc[0][j];
        const float c = -128.f * s;
        const int4 qq = qv[0][j];
        uint2 pk;
        pk.x = pack_bf16(fmaf((float)qq.x, s, c), fmaf((float)qq.y, s, c));
        pk.y = pack_bf16(fmaf((float)qq.z, s, c), fmaf((float)qq.w, s, c));
        *(uint2*)(&wt[0][(qrow + 16 * j) * BK + wpos]) = pk;
    }
#pragma unroll
    for (int j = 0; j < 8; ++j) {
        const int row = qrow + 16 * j;
        qv[0][j] = *(const int4*)(qbase + (size_t)row * IN_F + 1 * BK);
        sc[0][j] = scales[(size_t)(n0 + row) * SCB + 2 + qhi];
    }
    __syncthreads();

    for (int kt = 0; kt < NK; kt += 2) {
        GEMM_STEP_L(kt,     0, 0, 1);
        GEMM_STEP_L(kt + 1, 1, 1, 0);
    }

#pragma unroll
    for (int j = 0; j < 4; ++j) {
        const int col = n0 + wn * 64 + j * 16 + fr;
        const float bv = bias[col];
#pragma unroll
        for (int i = 0; i < 4; ++i) {
            const int rbase = m0 + wm * 64 + i * 16 + quad * 4;
#pragma unroll
            for (int r = 0; r < 4; ++r)
                out[(size_t)(rbase + r) * OUT_F + col] = acc[i][j][r] + bv;
        }
    }
}

extern "C" void kernel_launch(void* const* d_in, const int* in_sizes, int n_in,
                              void* d_out, int out_size, void* d_ws, size_t ws_size,
                              hipStream_t stream) {
    const float* x      = (const float*)d_in[0];
    const int*   q      = (const int*)d_in[1];
    const float* scales = (const float*)d_in[2];
    const float* lora_A = (const float*)d_in[3];
    const float* lora_B = (const float*)d_in[4];
    const float* bias   = (const float*)d_in[5];
    float* out = (float*)d_out;

    // ws layout: [0,16MB) xb bf16[1024][8192]; t fp32[1024][16]; then qu8
    const size_t xb_bytes = (size_t)M_TOT * IN_F * sizeof(uint16_t);   // 16 MB
    const size_t t_bytes  = (size_t)M_TOT * RANK * sizeof(float);      // 64 KB
    const size_t q8_off   = xb_bytes + t_bytes;                        // 16B-aligned
    const size_t q8_bytes = (size_t)OUT_F * IN_F;                      // 64 MB

    uint16_t* xb = (uint16_t*)d_ws;
    float*    t  = (float*)((char*)d_ws + xb_bytes);

    if (ws_size >= q8_off + q8_bytes) {
        uint8_t* qu8 = (uint8_t*)d_ws + q8_off;
        prep_kernel<<<2048, 256, 0, stream>>>(x, q, (uint2*)xb, (uint32_t*)qu8, t);
        lora_t_kernel<<<1024, 256, 0, stream>>>(xb, lora_A, t);
        gemm_u8_kernel<<<(M_TOT / BM) * (OUT_F / BN), 256, 0, stream>>>(
            xb, qu8, scales, t, lora_B, bias, out);
    } else {
        convert_kernel<<<M_TOT, 256, 0, stream>>>(x, (uint2*)xb, t);   // also zeroes t
        lora_t_kernel<<<1024, 256, 0, stream>>>(xb, lora_A, t);
        gemm_kernel<<<(M_TOT / BM) * (OUT_F / BN), 256, 0, stream>>>(
            xb, q, scales, t, lora_B, bias, out);
    }
}